// Round 4
// baseline (102.114 us; speedup 1.0000x reference)
//
#include <hip/hip_runtime.h>

#define MARGIN 9.0f
#define NB 32      // batch
#define NE 100000  // entities
#define ND 64      // dim
#define BLOCK 256
#define BSPLIT 4              // grid.y: split batch -> 1564 blocks, ~6.1 waves/SIMD
#define BPER (NB / BSPLIT)    // 8 b's per block

// Prep kernel (1 block): q[b][d] = emb_e[sub[b]][d] + emb_rel[rel[b]][d] -> ws[0..2047]
//                        qq[b]  = |q_b|^2                                -> ws[2048..2079]
__global__ __launch_bounds__(256) void transe_prep(
    const int* __restrict__ sub, const int* __restrict__ rel,
    const float* __restrict__ emb_e, const float* __restrict__ emb_rel,
    float* __restrict__ qws)
{
    __shared__ float qs[NB][ND];
    const int t = threadIdx.x;
    for (int i = t; i < NB * ND; i += 256) {
        const int b = i >> 6, d = i & 63;
        const float v = emb_e[(size_t)sub[b] * ND + d] + emb_rel[(size_t)rel[b] * ND + d];
        qs[b][d] = v;
        qws[i] = v;
    }
    __syncthreads();
    if (t < NB) {
        float s = 0.f;
#pragma unroll
        for (int d = 0; d < ND; ++d) { const float v = qs[t][d]; s += v * v; }
        qws[NB * ND + t] = s;
    }
}

// Score kernel: thread-per-entity; q via wave-uniform pointer -> scalar loads
// (s_load + v_fmac_f32 v,s,v). No LDS in the hot loop.
__global__ __launch_bounds__(BLOCK) void transe_score(
    const float* __restrict__ emb_e, const float* __restrict__ qws,
    float* __restrict__ out)
{
    int e = blockIdx.x * BLOCK + threadIdx.x;
    const bool valid = (e < NE);
    if (e >= NE) e = NE - 1;   // clamp: keep loads in-bounds, avoid divergence

    // Entity row -> 16 x float4 registers (256 B/thread). All 16 loads issued
    // back-to-back so vmcnt overlaps them.
    float4 r[16];
    const float4* rp = (const float4*)(emb_e + (size_t)e * ND);
#pragma unroll
    for (int i = 0; i < 16; ++i) r[i] = rp[i];

    float rr = 0.f;
#pragma unroll
    for (int i = 0; i < 16; ++i)
        rr += r[i].x * r[i].x + r[i].y * r[i].y + r[i].z * r[i].z + r[i].w * r[i].w;

    const int b0 = blockIdx.y * BPER;
#pragma unroll 4
    for (int bb = 0; bb < BPER; ++bb) {
        const int b = b0 + bb;
        const float* __restrict__ q = qws + b * ND;  // wave-uniform address -> SGPR
        float a0 = 0.f, a1 = 0.f, a2 = 0.f, a3 = 0.f;
#pragma unroll
        for (int i = 0; i < 16; ++i) {
            a0 = fmaf(q[4 * i + 0], r[i].x, a0);
            a1 = fmaf(q[4 * i + 1], r[i].y, a1);
            a2 = fmaf(q[4 * i + 2], r[i].z, a2);
            a3 = fmaf(q[4 * i + 3], r[i].w, a3);
        }
        const float dot = (a0 + a1) + (a2 + a3);
        float d2 = qws[NB * ND + b] + rr - 2.f * dot;   // |q|^2 + |r|^2 - 2 q.r
        d2 = fmaxf(d2, 0.f);
        if (valid) out[(size_t)b * NE + e] = MARGIN - sqrtf(d2);
    }
}

extern "C" void kernel_launch(void* const* d_in, const int* in_sizes, int n_in,
                              void* d_out, int out_size, void* d_ws, size_t ws_size,
                              hipStream_t stream)
{
    const int*   sub     = (const int*)d_in[0];
    const int*   rel     = (const int*)d_in[1];
    const float* emb_e   = (const float*)d_in[2];
    const float* emb_rel = (const float*)d_in[3];
    float*       out     = (float*)d_out;
    float*       qws     = (float*)d_ws;   // needs 2080 floats = 8.3 KB

    transe_prep<<<1, 256, 0, stream>>>(sub, rel, emb_e, emb_rel, qws);

    dim3 grid((NE + BLOCK - 1) / BLOCK, BSPLIT);  // 391 x 4
    transe_score<<<grid, BLOCK, 0, stream>>>(emb_e, qws, out);
}

// Round 5
// 96.817 us; speedup vs baseline: 1.0547x; 1.0547x over previous
//
#include <hip/hip_runtime.h>

#define MARGIN 9.0f
#define NB 32      // batch
#define NE 100000  // entities
#define ND 64      // dim
#define BLOCK 256
#define BSPLIT 2              // grid.y: best measured (96.8 us); BSPLIT=4 regressed (+5.3)
#define BPER (NB / BSPLIT)    // 16 b's per block

// Prep kernel (1 block): q[b][d] = emb_e[sub[b]][d] + emb_rel[rel[b]][d] -> ws[0..2047]
//                        qq[b]  = |q_b|^2                                -> ws[2048..2079]
__global__ __launch_bounds__(256) void transe_prep(
    const int* __restrict__ sub, const int* __restrict__ rel,
    const float* __restrict__ emb_e, const float* __restrict__ emb_rel,
    float* __restrict__ qws)
{
    __shared__ float qs[NB][ND];
    const int t = threadIdx.x;
    for (int i = t; i < NB * ND; i += 256) {
        const int b = i >> 6, d = i & 63;
        const float v = emb_e[(size_t)sub[b] * ND + d] + emb_rel[(size_t)rel[b] * ND + d];
        qs[b][d] = v;
        qws[i] = v;
    }
    __syncthreads();
    if (t < NB) {
        float s = 0.f;
#pragma unroll
        for (int d = 0; d < ND; ++d) { const float v = qs[t][d]; s += v * v; }
        qws[NB * ND + t] = s;
    }
}

// Score kernel: thread-per-entity; q via wave-uniform pointer -> scalar loads
// (s_load + v_fmac_f32 v,s,v). No LDS in the hot loop.
__global__ __launch_bounds__(BLOCK) void transe_score(
    const float* __restrict__ emb_e, const float* __restrict__ qws,
    float* __restrict__ out)
{
    int e = blockIdx.x * BLOCK + threadIdx.x;
    const bool valid = (e < NE);
    if (e >= NE) e = NE - 1;   // clamp: keep loads in-bounds, avoid divergence

    // Entity row -> 16 x float4 registers (256 B/thread). All 16 loads issued
    // back-to-back so vmcnt overlaps them.
    float4 r[16];
    const float4* rp = (const float4*)(emb_e + (size_t)e * ND);
#pragma unroll
    for (int i = 0; i < 16; ++i) r[i] = rp[i];

    float rr = 0.f;
#pragma unroll
    for (int i = 0; i < 16; ++i)
        rr += r[i].x * r[i].x + r[i].y * r[i].y + r[i].z * r[i].z + r[i].w * r[i].w;

    const int b0 = blockIdx.y * BPER;
#pragma unroll 4
    for (int bb = 0; bb < BPER; ++bb) {
        const int b = b0 + bb;
        const float* __restrict__ q = qws + b * ND;  // wave-uniform address -> SGPR
        float a0 = 0.f, a1 = 0.f, a2 = 0.f, a3 = 0.f;
#pragma unroll
        for (int i = 0; i < 16; ++i) {
            a0 = fmaf(q[4 * i + 0], r[i].x, a0);
            a1 = fmaf(q[4 * i + 1], r[i].y, a1);
            a2 = fmaf(q[4 * i + 2], r[i].z, a2);
            a3 = fmaf(q[4 * i + 3], r[i].w, a3);
        }
        const float dot = (a0 + a1) + (a2 + a3);
        float d2 = qws[NB * ND + b] + rr - 2.f * dot;   // |q|^2 + |r|^2 - 2 q.r
        d2 = fmaxf(d2, 0.f);
        if (valid) out[(size_t)b * NE + e] = MARGIN - sqrtf(d2);
    }
}

extern "C" void kernel_launch(void* const* d_in, const int* in_sizes, int n_in,
                              void* d_out, int out_size, void* d_ws, size_t ws_size,
                              hipStream_t stream)
{
    const int*   sub     = (const int*)d_in[0];
    const int*   rel     = (const int*)d_in[1];
    const float* emb_e   = (const float*)d_in[2];
    const float* emb_rel = (const float*)d_in[3];
    float*       out     = (float*)d_out;
    float*       qws     = (float*)d_ws;   // needs 2080 floats = 8.3 KB

    transe_prep<<<1, 256, 0, stream>>>(sub, rel, emb_e, emb_rel, qws);

    dim3 grid((NE + BLOCK - 1) / BLOCK, BSPLIT);  // 391 x 2
    transe_score<<<grid, BLOCK, 0, stream>>>(emb_e, qws, out);
}